// Round 6
// baseline (821.584 us; speedup 1.0000x reference)
//
#include <hip/hip_runtime.h>
#include <hip/hip_cooperative_groups.h>
#include <math.h>

namespace cg = cooperative_groups;

// GraphNet collapses algebraically: 1-channel input + node-shared weights =>
// every intermediate H = sum_k alpha_k[node] * basis_k. With T(f)=Agg(ns*nd*f),
// S=Agg(ns), A1=Agg(ns*x):
//   out = |nd*(b1*T^5(A1) + b2*T^4(S) + ... + b6*S) + bias5|
// R5: cooperative single-kernel path with occupancy-sized grid + checked
// launch; on any launch error, fall back to the proven R3 multi-kernel path.

#define CAP 64   // per-node CSR capacity; deg ~ Poisson(16), P(deg>=64) ~ 1e-13
#define TPB 256

// ---------------- cooperative all-in-one kernel ----------------
__global__ __launch_bounds__(TPB, 4) void k_net(
    const float* __restrict__ x, const int* __restrict__ src, const int* __restrict__ dst,
    const float* __restrict__ W0, const float* __restrict__ b0,
    const float* __restrict__ W1, const float* __restrict__ b1,
    const float* __restrict__ W2, const float* __restrict__ b2,
    const float* __restrict__ W3, const float* __restrict__ b3,
    const float* __restrict__ W4, const float* __restrict__ b4,
    const float* __restrict__ W5, const float* __restrict__ b5,
    int* __restrict__ outdeg, int* __restrict__ cursor, int* __restrict__ csr,
    double* __restrict__ carr, double* __restrict__ ndv, double* __restrict__ Facc,
    double2* __restrict__ pA, double2* __restrict__ pB,
    double* __restrict__ beta, float* __restrict__ out, int n, int E) {
  cg::grid_group grid = cg::this_grid();
  const int tid = blockIdx.x * TPB + threadIdx.x;
  const int P = gridDim.x * TPB;

  // phase 0: zero atomic targets (ws is poisoned each call)
  for (int v = tid; v < n; v += P) { outdeg[v] = 0; cursor[v] = 0; }
  grid.sync();

  // phase 1: padded CSR + out-degree histogram; block 0 also computes beta
  for (int e = tid; e < E; e += P) {
    int s = src[e], d = dst[e];
    atomicAdd(&outdeg[s], 1);
    int p = atomicAdd(&cursor[d], 1);
    if (p < CAP) csr[d * CAP + p] = s;
  }
  __shared__ double A[6 * 128], B[6 * 128];
  if (blockIdx.x == 0) {
    int t = threadIdx.x;
    if (t < 32) { A[0 * 128 + t] = (double)W0[t]; A[1 * 128 + t] = (double)b0[t]; }
    __syncthreads();
    if (t < 64) {
      for (int r = 0; r < 2; ++r) {
        double s = 0; for (int k = 0; k < 32; ++k) s += A[r * 128 + k] * (double)W1[k * 64 + t];
        B[r * 128 + t] = s;
      }
      B[2 * 128 + t] = (double)b1[t];
    }
    __syncthreads();
    if (t < 128) {
      for (int r = 0; r < 3; ++r) {
        double s = 0; for (int k = 0; k < 64; ++k) s += B[r * 128 + k] * (double)W2[k * 128 + t];
        A[r * 128 + t] = s;
      }
      A[3 * 128 + t] = (double)b2[t];
    }
    __syncthreads();
    if (t < 64) {
      for (int r = 0; r < 4; ++r) {
        double s = 0; for (int k = 0; k < 128; ++k) s += A[r * 128 + k] * (double)W3[k * 64 + t];
        B[r * 128 + t] = s;
      }
      B[4 * 128 + t] = (double)b3[t];
    }
    __syncthreads();
    if (t < 32) {
      for (int r = 0; r < 5; ++r) {
        double s = 0; for (int k = 0; k < 64; ++k) s += B[r * 128 + k] * (double)W4[k * 32 + t];
        A[r * 128 + t] = s;
      }
      A[5 * 128 + t] = (double)b4[t];
    }
    __syncthreads();
    if (t < 6) {
      double s = 0; for (int k = 0; k < 32; ++k) s += A[t * 128 + k] * (double)W5[k];
      beta[t] = s;
    }
  }
  grid.sync();

  // phase 2: norms + round-0 payload
  for (int v = tid; v < n; v += P) {
    int od = outdeg[v]; if (od < 1) od = 1;
    int id = cursor[v]; if (id < 1) id = 1;
    double ns = 1.0 / sqrt((double)od);
    double nd = 1.0 / sqrt((double)id);
    carr[v] = ns * nd;
    ndv[v] = nd;
    pA[v] = make_double2(ns * (double)x[v], ns);
  }
  grid.sync();

  double bet[6];
#pragma unroll
  for (int j = 0; j < 6; ++j) bet[j] = beta[j];
  const double b5d = (double)b5[0];

  // phases 3..8: six aggregation rounds, 4 sub-lanes per node
  const double2* pin = pA;
  double2* pout = pB;
  const int V = n * 4;
  for (int r = 0; r < 6; ++r) {
    for (int t2 = tid; t2 < V; t2 += P) {
      int v = t2 >> 2, sub = t2 & 3;
      int cnt = cursor[v]; if (cnt > CAP) cnt = CAP;
      const int* row = csr + v * CAP;
      double aa = 0.0, as = 0.0;
      for (int i = sub; i < cnt; i += 4) {
        double2 p = pin[row[i]];
        aa += p.x; as += p.y;
      }
      aa += __shfl_xor(aa, 1); as += __shfl_xor(as, 1);
      aa += __shfl_xor(aa, 2); as += __shfl_xor(as, 2);
      if (sub == 0) {
        if (r == 5) {
          double res = ndv[v] * (bet[0] * aa + Facc[v]) + b5d;
          out[v] = (float)fabs(res);
        } else {
          if (r == 0) Facc[v] = bet[5] * as;
          else        Facc[v] += bet[5 - r] * as;
          double cv = carr[v];
          pout[v] = make_double2(cv * aa, cv * as);
        }
      }
    }
    if (r < 5) grid.sync();
    const double2* tmp = pin; pin = pout; pout = (double2*)tmp;
  }
}

// ---------------- fallback multi-kernel path (proven R3) ----------------
__global__ void k_outdeg(const int* __restrict__ src, int* __restrict__ outdeg, int E) {
  int e = blockIdx.x * blockDim.x + threadIdx.x;
  if (e < E) atomicAdd(&outdeg[src[e]], 1);
}

__global__ void k_fill(const int* __restrict__ src, const int* __restrict__ dst,
                       int* __restrict__ cursor, int* __restrict__ csr, int E) {
  int e = blockIdx.x * blockDim.x + threadIdx.x;
  if (e < E) {
    int d = dst[e];
    int p = atomicAdd(&cursor[d], 1);
    if (p < CAP) csr[(size_t)d * CAP + p] = src[e];
  }
}

__global__ void k_norms(const int* __restrict__ outdeg, const int* __restrict__ indeg,
                        const float* __restrict__ x, double* __restrict__ c,
                        double* __restrict__ ndv, double2* __restrict__ pair0, int n) {
  int v = blockIdx.x * blockDim.x + threadIdx.x;
  if (v < n) {
    int od = outdeg[v]; if (od < 1) od = 1;
    int id = indeg[v];  if (id < 1) id = 1;
    double ns = 1.0 / sqrt((double)od);
    double nd = 1.0 / sqrt((double)id);
    c[v] = ns * nd;
    ndv[v] = nd;
    pair0[v] = make_double2(ns * (double)x[v], ns);
  }
}

__global__ __launch_bounds__(128) void k_beta(
    const float* __restrict__ W0, const float* __restrict__ b0,
    const float* __restrict__ W1, const float* __restrict__ b1,
    const float* __restrict__ W2, const float* __restrict__ b2,
    const float* __restrict__ W3, const float* __restrict__ b3,
    const float* __restrict__ W4, const float* __restrict__ b4,
    const float* __restrict__ W5, double* __restrict__ beta) {
  __shared__ double A[6 * 128], B[6 * 128];
  int t = threadIdx.x;
  if (t < 32) { A[0 * 128 + t] = (double)W0[t]; A[1 * 128 + t] = (double)b0[t]; }
  __syncthreads();
  if (t < 64) {
    for (int r = 0; r < 2; ++r) {
      double s = 0; for (int k = 0; k < 32; ++k) s += A[r * 128 + k] * (double)W1[k * 64 + t];
      B[r * 128 + t] = s;
    }
    B[2 * 128 + t] = (double)b1[t];
  }
  __syncthreads();
  if (t < 128) {
    for (int r = 0; r < 3; ++r) {
      double s = 0; for (int k = 0; k < 64; ++k) s += B[r * 128 + k] * (double)W2[k * 128 + t];
      A[r * 128 + t] = s;
    }
    A[3 * 128 + t] = (double)b2[t];
  }
  __syncthreads();
  if (t < 64) {
    for (int r = 0; r < 4; ++r) {
      double s = 0; for (int k = 0; k < 128; ++k) s += A[r * 128 + k] * (double)W3[k * 64 + t];
      B[r * 128 + t] = s;
    }
    B[4 * 128 + t] = (double)b3[t];
  }
  __syncthreads();
  if (t < 32) {
    for (int r = 0; r < 5; ++r) {
      double s = 0; for (int k = 0; k < 64; ++k) s += B[r * 128 + k] * (double)W4[k * 32 + t];
      A[r * 128 + t] = s;
    }
    A[5 * 128 + t] = (double)b4[t];
  }
  __syncthreads();
  if (t < 6) {
    double s = 0; for (int k = 0; k < 32; ++k) s += A[t * 128 + k] * (double)W5[k];
    beta[t] = s;
  }
}

__global__ __launch_bounds__(256) void k_round(
    const double2* __restrict__ pin, double2* __restrict__ pout,
    double* __restrict__ Facc, const double* __restrict__ beta, int bIdx,
    const double* __restrict__ c, const double* __restrict__ ndv,
    const float* __restrict__ b5, float* __restrict__ out,
    const int* __restrict__ deg, const int* __restrict__ csr, int n, int mode) {
  int tid = blockIdx.x * blockDim.x + threadIdx.x;
  int v = tid >> 3, sub = tid & 7;
  if (v >= n) return;
  int cnt = deg[v]; if (cnt > CAP) cnt = CAP;
  const int* row = csr + (size_t)v * CAP;
  double aa = 0.0, as = 0.0;
  for (int i = sub; i < cnt; i += 8) {
    double2 p = pin[row[i]];
    aa += p.x; as += p.y;
  }
  aa += __shfl_xor(aa, 1); as += __shfl_xor(as, 1);
  aa += __shfl_xor(aa, 2); as += __shfl_xor(as, 2);
  aa += __shfl_xor(aa, 4); as += __shfl_xor(as, 4);
  if (sub != 0) return;
  if (mode == 2) {
    double r = ndv[v] * (beta[0] * aa + Facc[v]) + (double)b5[0];
    out[v] = (float)fabs(r);
  } else {
    if (mode == 0) Facc[v] = beta[bIdx] * as;
    else           Facc[v] += beta[bIdx] * as;
    double cv = c[v];
    pout[v] = make_double2(cv * aa, cv * as);
  }
}

extern "C" void kernel_launch(void* const* d_in, const int* in_sizes, int n_in,
                              void* d_out, int out_size, void* d_ws, size_t ws_size,
                              hipStream_t stream) {
  const float* x  = (const float*)d_in[0];
  const int* src  = (const int*)d_in[1];
  const int* dst  = (const int*)d_in[2];
  const float* W0 = (const float*)d_in[3];  const float* b0 = (const float*)d_in[4];
  const float* W1 = (const float*)d_in[5];  const float* b1 = (const float*)d_in[6];
  const float* W2 = (const float*)d_in[7];  const float* b2 = (const float*)d_in[8];
  const float* W3 = (const float*)d_in[9];  const float* b3 = (const float*)d_in[10];
  const float* W4 = (const float*)d_in[11]; const float* b4 = (const float*)d_in[12];
  const float* W5 = (const float*)d_in[13]; const float* b5 = (const float*)d_in[14];
  int n = in_sizes[0];
  int E = in_sizes[1];
  float* out = (float*)d_out;

  char* wp = (char*)d_ws;
  size_t off = 0;
  auto alloc = [&](size_t bytes) -> char* {
    char* p = wp + off;
    off += (bytes + 255) & ~(size_t)255;
    return p;
  };
  int* deg2     = (int*)alloc((size_t)2 * n * 4);      // outdeg | cursor contiguous
  int* outdeg   = deg2;
  int* cursor   = deg2 + n;
  int* csr      = (int*)alloc((size_t)n * CAP * 4);    // 25.6 MB padded CSR
  double* carr  = (double*)alloc((size_t)n * 8);
  double* ndv   = (double*)alloc((size_t)n * 8);
  double* Facc  = (double*)alloc((size_t)n * 8);
  double2* pA   = (double2*)alloc((size_t)n * 16);
  double2* pB   = (double2*)alloc((size_t)n * 16);
  double* beta  = (double*)alloc(8 * 8);

  // ---- try the cooperative single-kernel path, sized to real occupancy ----
  int occ = 0;
  hipError_t qerr = hipOccupancyMaxActiveBlocksPerMultiprocessor(&occ, k_net, TPB, 0);
  int dev = 0; hipGetDevice(&dev);
  hipDeviceProp_t prop;
  hipError_t perr = hipGetDeviceProperties(&prop, dev);
  hipError_t lerr = hipErrorUnknown;
  if (qerr == hipSuccess && perr == hipSuccess && occ > 0) {
    int nblk = occ * prop.multiProcessorCount;
    if (nblk > 1024) nblk = 1024;
    void* args[] = {
      (void*)&x, (void*)&src, (void*)&dst,
      (void*)&W0, (void*)&b0, (void*)&W1, (void*)&b1, (void*)&W2, (void*)&b2,
      (void*)&W3, (void*)&b3, (void*)&W4, (void*)&b4, (void*)&W5, (void*)&b5,
      (void*)&outdeg, (void*)&cursor, (void*)&csr,
      (void*)&carr, (void*)&ndv, (void*)&Facc,
      (void*)&pA, (void*)&pB, (void*)&beta, (void*)&out,
      (void*)&n, (void*)&E
    };
    lerr = hipLaunchCooperativeKernel((void*)k_net, dim3(nblk), dim3(TPB), args, 0, stream);
  }
  if (lerr == hipSuccess) return;

  // ---- fallback: proven multi-kernel pipeline ----
  hipMemsetAsync(deg2, 0, (size_t)2 * n * 4, stream);
  const int tb = 256;
  const int ge = (E + tb - 1) / tb;
  k_outdeg<<<ge, tb, 0, stream>>>(src, outdeg, E);
  k_fill<<<ge, tb, 0, stream>>>(src, dst, cursor, csr, E);
  k_norms<<<(n + tb - 1) / tb, tb, 0, stream>>>(outdeg, cursor, x, carr, ndv, pA, n);
  k_beta<<<1, 128, 0, stream>>>(W0, b0, W1, b1, W2, b2, W3, b3, W4, b4, W5, beta);
  const int gn8 = (8 * n + tb - 1) / tb;
  k_round<<<gn8, tb, 0, stream>>>(pA, pB, Facc, beta, 5, carr, ndv, b5, out, cursor, csr, n, 0);
  k_round<<<gn8, tb, 0, stream>>>(pB, pA, Facc, beta, 4, carr, ndv, b5, out, cursor, csr, n, 1);
  k_round<<<gn8, tb, 0, stream>>>(pA, pB, Facc, beta, 3, carr, ndv, b5, out, cursor, csr, n, 1);
  k_round<<<gn8, tb, 0, stream>>>(pB, pA, Facc, beta, 2, carr, ndv, b5, out, cursor, csr, n, 1);
  k_round<<<gn8, tb, 0, stream>>>(pA, pB, Facc, beta, 1, carr, ndv, b5, out, cursor, csr, n, 1);
  k_round<<<gn8, tb, 0, stream>>>(pB, pA, Facc, beta, 0, carr, ndv, b5, out, cursor, csr, n, 2);
}

// Round 7
// 363.414 us; speedup vs baseline: 2.2607x; 2.2607x over previous
//
#include <hip/hip_runtime.h>
#include <math.h>

// GraphNet collapses algebraically: 1-channel input + node-shared weights =>
// every intermediate H = sum_k alpha_k[node] * basis_k. With T(f)=Agg(ns*nd*f),
// S=Agg(ns), A1=Agg(ns*x):
//   out = |nd*(b1*T^5(A1) + b2*T^4(S) + ... + b6*S) + bias5|
// R6 verdict: cooperative fusion loses 3x (grid.sync => cross-XCD L2
// writeback/invalidate => rounds re-fetch from HBM at miss latency).
// R7: multi-kernel, fused build (outdeg+cursor+csr in one pass), beta folded
// into norms' block 0, 16 sub-lanes/node rounds.

#define CAP 64  // per-node CSR capacity; deg ~ Poisson(16), P(deg>=64) ~ 1e-18

// One pass over edges: out-degree histogram + padded-CSR fill.
// cursor[d] ends as in-degree. 4.8M scattered 32B txns — the txn-rate floor.
__global__ void k_build(const int* __restrict__ src, const int* __restrict__ dst,
                        int* __restrict__ outdeg, int* __restrict__ cursor,
                        int* __restrict__ csr, int E) {
  int e = blockIdx.x * blockDim.x + threadIdx.x;
  if (e < E) {
    int s = src[e], d = dst[e];
    atomicAdd(&outdeg[s], 1);
    int p = atomicAdd(&cursor[d], 1);
    if (p < CAP) csr[(size_t)d * CAP + p] = s;
  }
}

// norms + round-0 payload; block 0 additionally computes beta[6] in f64:
// beta = (((([W0;b0]@W1 ; b1)@W2 ; b2)@W3 ; b3)@W4 ; b4)@W5
__global__ __launch_bounds__(256) void k_normsbeta(
    const int* __restrict__ outdeg, const int* __restrict__ indeg,
    const float* __restrict__ x, double* __restrict__ c,
    double* __restrict__ ndv, double2* __restrict__ pair0,
    const float* __restrict__ W0, const float* __restrict__ b0,
    const float* __restrict__ W1, const float* __restrict__ b1,
    const float* __restrict__ W2, const float* __restrict__ b2,
    const float* __restrict__ W3, const float* __restrict__ b3,
    const float* __restrict__ W4, const float* __restrict__ b4,
    const float* __restrict__ W5, double* __restrict__ beta, int n) {
  int v = blockIdx.x * blockDim.x + threadIdx.x;
  if (v < n) {
    int od = outdeg[v]; if (od < 1) od = 1;
    int id = indeg[v];  if (id < 1) id = 1;
    double ns = 1.0 / sqrt((double)od);
    double nd = 1.0 / sqrt((double)id);
    c[v] = ns * nd;
    ndv[v] = nd;
    pair0[v] = make_double2(ns * (double)x[v], ns);
  }
  if (blockIdx.x == 0) {
    __shared__ double A[6 * 128], B[6 * 128];
    int t = threadIdx.x;
    if (t < 32) { A[0 * 128 + t] = (double)W0[t]; A[1 * 128 + t] = (double)b0[t]; }
    __syncthreads();
    if (t < 64) {
      for (int r = 0; r < 2; ++r) {
        double s = 0; for (int k = 0; k < 32; ++k) s += A[r * 128 + k] * (double)W1[k * 64 + t];
        B[r * 128 + t] = s;
      }
      B[2 * 128 + t] = (double)b1[t];
    }
    __syncthreads();
    if (t < 128) {
      for (int r = 0; r < 3; ++r) {
        double s = 0; for (int k = 0; k < 64; ++k) s += B[r * 128 + k] * (double)W2[k * 128 + t];
        A[r * 128 + t] = s;
      }
      A[3 * 128 + t] = (double)b2[t];
    }
    __syncthreads();
    if (t < 64) {
      for (int r = 0; r < 4; ++r) {
        double s = 0; for (int k = 0; k < 128; ++k) s += A[r * 128 + k] * (double)W3[k * 64 + t];
        B[r * 128 + t] = s;
      }
      B[4 * 128 + t] = (double)b3[t];
    }
    __syncthreads();
    if (t < 32) {
      for (int r = 0; r < 5; ++r) {
        double s = 0; for (int k = 0; k < 64; ++k) s += B[r * 128 + k] * (double)W4[k * 32 + t];
        A[r * 128 + t] = s;
      }
      A[5 * 128 + t] = (double)b4[t];
    }
    __syncthreads();
    if (t < 6) {
      double s = 0; for (int k = 0; k < 32; ++k) s += A[t * 128 + k] * (double)W5[k];
      beta[t] = s;
    }
  }
}

// One aggregation round. 16 sub-lanes per node (deg~16 -> ~1 gather iter each);
// fixed-order shuffle reduce keeps f64 determinism.
// mode 0: Facc  = beta[bIdx]*As; write pout = c*(Aa,As)
// mode 1: Facc += beta[bIdx]*As; write pout
// mode 2: out[v] = |nd*(beta[0]*Aa + Facc) + b5|
__global__ __launch_bounds__(256) void k_round(
    const double2* __restrict__ pin, double2* __restrict__ pout,
    double* __restrict__ Facc, const double* __restrict__ beta, int bIdx,
    const double* __restrict__ c, const double* __restrict__ ndv,
    const float* __restrict__ b5, float* __restrict__ out,
    const int* __restrict__ deg, const int* __restrict__ csr, int n, int mode) {
  int tid = blockIdx.x * blockDim.x + threadIdx.x;
  int v = tid >> 4, sub = tid & 15;
  if (v >= n) return;
  int cnt = deg[v]; if (cnt > CAP) cnt = CAP;
  const int* row = csr + (size_t)v * CAP;
  double aa = 0.0, as = 0.0;
  for (int i = sub; i < cnt; i += 16) {
    double2 p = pin[row[i]];
    aa += p.x; as += p.y;
  }
  aa += __shfl_xor(aa, 1); as += __shfl_xor(as, 1);
  aa += __shfl_xor(aa, 2); as += __shfl_xor(as, 2);
  aa += __shfl_xor(aa, 4); as += __shfl_xor(as, 4);
  aa += __shfl_xor(aa, 8); as += __shfl_xor(as, 8);
  if (sub != 0) return;
  if (mode == 2) {
    double r = ndv[v] * (beta[0] * aa + Facc[v]) + (double)b5[0];
    out[v] = (float)fabs(r);
  } else {
    if (mode == 0) Facc[v] = beta[bIdx] * as;
    else           Facc[v] += beta[bIdx] * as;
    double cv = c[v];
    pout[v] = make_double2(cv * aa, cv * as);
  }
}

extern "C" void kernel_launch(void* const* d_in, const int* in_sizes, int n_in,
                              void* d_out, int out_size, void* d_ws, size_t ws_size,
                              hipStream_t stream) {
  const float* x  = (const float*)d_in[0];
  const int* src  = (const int*)d_in[1];
  const int* dst  = (const int*)d_in[2];
  const float* W0 = (const float*)d_in[3];  const float* b0 = (const float*)d_in[4];
  const float* W1 = (const float*)d_in[5];  const float* b1 = (const float*)d_in[6];
  const float* W2 = (const float*)d_in[7];  const float* b2 = (const float*)d_in[8];
  const float* W3 = (const float*)d_in[9];  const float* b3 = (const float*)d_in[10];
  const float* W4 = (const float*)d_in[11]; const float* b4 = (const float*)d_in[12];
  const float* W5 = (const float*)d_in[13]; const float* b5 = (const float*)d_in[14];
  const int n = in_sizes[0];
  const int E = in_sizes[1];
  float* out = (float*)d_out;

  char* wp = (char*)d_ws;
  size_t off = 0;
  auto alloc = [&](size_t bytes) -> char* {
    char* p = wp + off;
    off += (bytes + 255) & ~(size_t)255;
    return p;
  };
  int* deg2     = (int*)alloc((size_t)2 * n * 4);      // outdeg | cursor contiguous
  int* outdeg   = deg2;
  int* cursor   = deg2 + n;
  int* csr      = (int*)alloc((size_t)n * CAP * 4);    // 25.6 MB padded CSR
  double* carr  = (double*)alloc((size_t)n * 8);
  double* ndv   = (double*)alloc((size_t)n * 8);
  double* Facc  = (double*)alloc((size_t)n * 8);
  double2* pA   = (double2*)alloc((size_t)n * 16);
  double2* pB   = (double2*)alloc((size_t)n * 16);
  double* beta  = (double*)alloc(8 * 8);

  hipMemsetAsync(deg2, 0, (size_t)2 * n * 4, stream);

  const int tb = 256;
  k_build<<<(E + tb - 1) / tb, tb, 0, stream>>>(src, dst, outdeg, cursor, csr, E);
  k_normsbeta<<<(n + tb - 1) / tb, tb, 0, stream>>>(
      outdeg, cursor, x, carr, ndv, pA,
      W0, b0, W1, b1, W2, b2, W3, b3, W4, b4, W5, beta, n);

  const int gn16 = (16 * n + tb - 1) / tb;
  // r0: (A1,S) from (ns*x, ns); Facc = beta6*S
  k_round<<<gn16, tb, 0, stream>>>(pA, pB, Facc, beta, 5, carr, ndv, b5, out, cursor, csr, n, 0);
  // r1..r4: T applications; Facc += beta_{6-k} * T^k(S)
  k_round<<<gn16, tb, 0, stream>>>(pB, pA, Facc, beta, 4, carr, ndv, b5, out, cursor, csr, n, 1);
  k_round<<<gn16, tb, 0, stream>>>(pA, pB, Facc, beta, 3, carr, ndv, b5, out, cursor, csr, n, 1);
  k_round<<<gn16, tb, 0, stream>>>(pB, pA, Facc, beta, 2, carr, ndv, b5, out, cursor, csr, n, 1);
  k_round<<<gn16, tb, 0, stream>>>(pA, pB, Facc, beta, 1, carr, ndv, b5, out, cursor, csr, n, 1);
  // r5: out = |nd*(beta1*T^5(A1) + Facc) + b5|
  k_round<<<gn16, tb, 0, stream>>>(pB, pA, Facc, beta, 0, carr, ndv, b5, out, cursor, csr, n, 2);
}